// Round 5
// baseline (379.900 us; speedup 1.0000x reference)
//
#include <hip/hip_runtime.h>
#include <math.h>

#define N_CH 17
#define IN_H 64
#define IN_W 32
#define HW 128

// s_in: [2 bufs][2 halves][68 rows x 32 cols] ; rows 0,1,66,67 zero pads,
//       data floats [64,2112) per half-region.
// tmp : [2 halves][16 rows x stride 37], cols 0,1,34,35 zero pads.
#define SIN_CH 2176
#define TMP_STRIDE 37
#define TMP_CH (16 * TMP_STRIDE)   // 592
#define EDGE (32.f / 28.f)

#define W0 (1.f/32.f)
#define W1 (3.f/32.f)
#define W2 (5.f/32.f)
#define W3 (7.f/32.f)

// 8-tap on padded rows starting at relative row R (stride 32 floats)
#define TAP8(b, R) (W0*(b)[(R)*32]     + W1*(b)[((R)+1)*32] + W2*(b)[((R)+2)*32] \
                  + W3*(b)[((R)+3)*32] + W3*(b)[((R)+4)*32] + W2*(b)[((R)+5)*32] \
                  + W1*(b)[((R)+6)*32] + W0*(b)[((R)+7)*32])

// LDS-visibility barrier that does NOT touch vmcnt (async loads stay in flight)
#define BAR_LGKM() asm volatile("s_waitcnt lgkmcnt(0)\n\ts_barrier" ::: "memory")
// Publish async global->LDS: keep the 4 newest loads in flight, drain older
#define BAR_VM4()  asm volatile("s_waitcnt vmcnt(4)\n\ts_barrier" ::: "memory")

// async 16B global->LDS (dest = wave-uniform base + lane*16; our per-lane
// pointers are exactly base + lane*16 within each wave)
__device__ __forceinline__ void gll16(const float* g, float* l) {
    __builtin_amdgcn_global_load_lds(
        (const __attribute__((address_space(1))) void*)g,
        (__attribute__((address_space(3))) void*)l, 16, 0, 0);
}

__global__ __launch_bounds__(256)
void heatmap_kernel(const float* __restrict__ x,
                    float* __restrict__ out_heat,   // [N,3,16,8]
                    float* __restrict__ out_mr,     // [N,3]
                    float* __restrict__ out_mi) {   // [N,17,2]
    const int n = blockIdx.x;
    const int t = threadIdx.x;
    const int w = t >> 6, l = t & 63;
    const int half = t >> 7;          // 0: even channels (waves 0,1), 1: odd (2,3)
    const int tl = t & 127;
    const int col = tl & 31, q = tl >> 5;   // stage1: owns output rows 4q..4q+3
    const int p = tl;                        // stage2 position 0..127
    const int r2 = p >> 3, oc = p & 7;
    const int hpos = w & 1;

    __shared__ float s_in[2][2 * SIN_CH];    // 34816 B (buf ping-pong)
    __shared__ float s_tmp[2 * TMP_CH];      // 4736 B
    __shared__ float s_cval[N_CH * 2];
    __shared__ int   s_cidx[N_CH * 2];

    float* st = s_tmp + half * TMP_CH;

    // zero pads: both bufs, both halves (t: 4 groups of 64 cover buf x half)
    {
        int pb = t >> 7, ph = (t >> 6) & 1;
        float* r = &s_in[pb][ph * SIN_CH];
        r[l] = 0.f;           // rows 0,1
        r[2112 + l] = 0.f;    // rows 66,67
        // second buf's other combos are covered because (pb,ph) spans all 4? No:
        // t<128 -> pb=0 (ph=0,1); t>=128 -> pb=1 (ph=0,1). All 4 covered.
    }
    if (t < 128) {           // tmp pad cols
        int ch = t >> 6, rr = (t >> 2) & 15, jj = t & 3;
        int cc = (jj < 2) ? jj : jj + 32;
        s_tmp[ch * TMP_CH + rr * TMP_STRIDE + cc] = 0.f;
    }
    asm volatile("s_waitcnt lgkmcnt(0)" ::: "memory");  // own pad writes done

    const float* xn = x + (size_t)n * N_CH * IN_H * IN_W;
    float ga0 = 0.f, ga1 = 0.f, ga2 = 0.f;

    // prologue: async-load channel c=half into buf 0
    {
        const float* src = xn + (size_t)half * 2048;
        float* dst = &s_in[0][half * SIN_CH + 64];
#pragma unroll
        for (int j = 0; j < 4; ++j)
            gll16(src + 4 * (tl + 128 * j), dst + 4 * (tl + 128 * j));
    }

#pragma unroll
    for (int i = 0; i < 9; ++i) {
        const int c = 2 * i + half;
        const bool valid = (c < N_CH);

        // prefetch next channel into the other buf (stays in flight past BAR_VM4)
        {
            int cn = 2 * (i + 1) + half;
            if (cn > 16) cn = 16;   // clamped re-read (L2-hit); keeps counts uniform
            const float* src = xn + (size_t)cn * 2048;
            float* dst = &s_in[(i + 1) & 1][half * SIN_CH + 64];
#pragma unroll
            for (int j = 0; j < 4; ++j)
                gll16(src + 4 * (tl + 128 * j), dst + 4 * (tl + 128 * j));
        }

        BAR_VM4();   // older loads (current buf) complete; 4 newest still flying

        // stage 1 (H 64->16) from current buf
        const float* sw = &s_in[i & 1][half * SIN_CH];
        const float* b = sw + (16 * q) * 32 + col;
        float o0 = TAP8(b, 0);
        float o1 = TAP8(b, 4);
        float o2 = TAP8(b, 8);
        float o3 = TAP8(b, 12);
        if (q == 0) o0 *= EDGE;
        if (q == 3) o3 *= EDGE;

        BAR_LGKM();  // all s_in reads retired -> next iter may overwrite that buf

        st[(4 * q + 0) * TMP_STRIDE + 2 + col] = o0;
        st[(4 * q + 1) * TMP_STRIDE + 2 + col] = o1;
        st[(4 * q + 2) * TMP_STRIDE + 2 + col] = o2;
        st[(4 * q + 3) * TMP_STRIDE + 2 + col] = o3;

        // stage 2 (W 32->8): wave-local (this wave wrote exactly these tmp rows)
        const float* b2 = st + r2 * TMP_STRIDE + 4 * oc;
        float o = W0*b2[0] + W1*b2[1] + W2*b2[2] + W3*b2[3]
                + W3*b2[4] + W2*b2[5] + W1*b2[6] + W0*b2[7];
        if (oc == 0 || oc == 7) o *= EDGE;

        if (valid) {
            if (c < 5)       ga0 += o;
            else if (c < 11) ga1 += o;
            else             ga2 += o;

            float bv = o; int bi = p;
#pragma unroll
            for (int off = 32; off >= 1; off >>= 1) {
                float ov = __shfl_down(bv, off);
                int   oi = __shfl_down(bi, off);
                if (ov > bv || (ov == bv && oi < bi)) { bv = ov; bi = oi; }
            }
            if (l == 0) { s_cval[2 * c + hpos] = bv; s_cidx[2 * c + hpos] = bi; }
        }
    }

    __syncthreads();                 // drains vmcnt(0) incl. dead clamped loads
    float* s_part = &s_in[0][0];     // overlay [2][3][128] on dead buffer
    s_part[(half * 3 + 0) * HW + p] = ga0;
    s_part[(half * 3 + 1) * HW + p] = ga1;
    s_part[(half * 3 + 2) * HW + p] = ga2;
    __syncthreads();

    if (w < 3) {
        const int g = w;   // softmax over 128 positions of group g, one wave
        float v0 = s_part[g * HW + l]      + s_part[(3 + g) * HW + l];
        float v1 = s_part[g * HW + 64 + l] + s_part[(3 + g) * HW + 64 + l];
        float m = fmaxf(v0, v1);
#pragma unroll
        for (int off = 1; off < 64; off <<= 1) m = fmaxf(m, __shfl_xor(m, off));
        float e0 = expf(v0 - m), e1 = expf(v1 - m);
        float s = e0 + e1;
#pragma unroll
        for (int off = 1; off < 64; off <<= 1) s += __shfl_xor(s, off);
        float inv = 1.f / s;
        float* dsto = out_heat + ((size_t)n * 3 + g) * HW;
        dsto[l]      = e0 * inv;
        dsto[l + 64] = e1 * inv;
    } else {
        if (l < N_CH) {
            int c = l;
            float v0 = s_cval[2 * c], v1 = s_cval[2 * c + 1];
            int i0 = s_cidx[2 * c], i1 = s_cidx[2 * c + 1];
            int bi = (v1 > v0) ? i1 : i0;     // tie -> lower-index half
            float* mi = out_mi + ((size_t)n * N_CH + c) * 2;
            mi[0] = (float)(bi & 7);
            mi[1] = (float)(bi >> 3);
        }
        if (l < 3) {
            int lo = (l == 0) ? 0 : ((l == 1) ? 5 : 11);
            int hi = (l == 0) ? 5 : ((l == 1) ? 11 : 17);
            float acc = 0.f;
            for (int c2 = lo; c2 < hi; ++c2)
                acc += fmaxf(s_cval[2 * c2], s_cval[2 * c2 + 1]);
            out_mr[(size_t)n * 3 + l] = acc / (float)(hi - lo);
        }
    }
}

extern "C" void kernel_launch(void* const* d_in, const int* in_sizes, int n_in,
                              void* d_out, int out_size, void* d_ws, size_t ws_size,
                              hipStream_t stream) {
    const float* x = (const float*)d_in[0];
    float* out = (float*)d_out;
    const int N = in_sizes[0] / (N_CH * IN_H * IN_W);  // 2048
    float* out_heat = out;                             // N*3*128
    float* out_mr   = out_heat + (size_t)N * 3 * HW;   // N*3
    float* out_mi   = out_mr + (size_t)N * 3;          // N*17*2
    heatmap_kernel<<<dim3(N), dim3(256), 0, stream>>>(x, out_heat, out_mr, out_mi);
}

// Round 6
// 377.850 us; speedup vs baseline: 1.0054x; 1.0054x over previous
//
#include <hip/hip_runtime.h>
#include <math.h>

#define N_CH 17
#define HW 128

// Per-WAVE private LDS slices (all producer/consumer deps are same-wave ->
// zero block barriers in the main loop; compiler's own lgkmcnt ordering is
// sufficient. The only __syncthreads is the final cross-wave combine.)
//   s_in slice: 68 rows x 32 cols (rows 0,1,66,67 zero pads; data [64,2112))
//   tmp  slice: 16 rows x stride 37 (cols 0,1,34,35 zero pads; data at col+2)
#define SIN_W 2176
#define TMP_STRIDE 37
#define TMP_W (16 * TMP_STRIDE)   // 592
#define EDGE (32.f / 28.f)

#define W0 (1.f/32.f)
#define W1 (3.f/32.f)
#define W2 (5.f/32.f)
#define W3 (7.f/32.f)

// 8-tap on padded rows starting at relative row R (stride 32 floats)
#define TAP8(b, R) (W0*(b)[(R)*32]     + W1*(b)[((R)+1)*32] + W2*(b)[((R)+2)*32] \
                  + W3*(b)[((R)+3)*32] + W3*(b)[((R)+4)*32] + W2*(b)[((R)+5)*32] \
                  + W1*(b)[((R)+6)*32] + W0*(b)[((R)+7)*32])

__global__ __launch_bounds__(256)
void heatmap_kernel(const float* __restrict__ x,
                    float* __restrict__ out_heat,   // [N,3,16,8]
                    float* __restrict__ out_mr,     // [N,3]
                    float* __restrict__ out_mi) {   // [N,17,2]
    const int n = blockIdx.x;
    const int t = threadIdx.x;
    const int w = t >> 6, l = t & 63;

    __shared__ float s_in[4 * SIN_W];    // 34816 B (overlaid by s_part later)
    __shared__ float s_tmp[4 * TMP_W];   // 9472 B
    __shared__ float s_cval[N_CH];

    float* sw = s_in + w * SIN_W;
    float* st = s_tmp + w * TMP_W;

    // private pad init — same-wave visibility, no barrier needed
    sw[l] = 0.f;            // padded rows 0,1
    sw[2112 + l] = 0.f;     // padded rows 66,67
    {
        int rr = l >> 2, jj = l & 3;
        int cc = (jj < 2) ? jj : jj + 32;
        st[rr * TMP_STRIDE + cc] = 0.f;
    }

    const float* xn = x + (size_t)n * N_CH * 2048;
    const int col = l & 31, h = l >> 5;   // stage1: col, row-half
    const int oc = l & 7;                 // stage2 output col (same for l, l+64)
    const float cs2 = (oc == 0 || oc == 7) ? EDGE : 1.f;

    // group sums for positions l (lo) and l+64 (hi) — scalars, never arrays
    float ga0l = 0.f, ga0h = 0.f, ga1l = 0.f, ga1h = 0.f, ga2l = 0.f, ga2h = 0.f;

    // single-buffer prefetch regs: ds_write consumes them before reload
    float4 v0, v1, v2, v3, v4, v5, v6, v7;
    {
        const float4* src = (const float4*)(xn + (size_t)w * 2048);
        v0 = src[l];       v1 = src[l + 64];  v2 = src[l + 128]; v3 = src[l + 192];
        v4 = src[l + 256]; v5 = src[l + 320]; v6 = src[l + 384]; v7 = src[l + 448];
    }

#pragma unroll
    for (int i = 0; i < 5; ++i) {
        const int c = w + 4 * i;          // wave-uniform
        if (c >= N_CH) break;             // waves 1-3 run 4 iters, wave 0 runs 5

        // stage current channel regs -> private s_in slice (rows 2..65)
        {
            float4* dst = (float4*)(sw + 64);
            dst[l]       = v0; dst[l + 64]  = v1; dst[l + 128] = v2; dst[l + 192] = v3;
            dst[l + 256] = v4; dst[l + 320] = v5; dst[l + 384] = v6; dst[l + 448] = v7;
        }

        // prefetch this wave's next channel; flies during stage1+stage2
        if (c + 4 < N_CH) {
            const float4* src = (const float4*)(xn + (size_t)(c + 4) * 2048);
            v0 = src[l];       v1 = src[l + 64];  v2 = src[l + 128]; v3 = src[l + 192];
            v4 = src[l + 256]; v5 = src[l + 320]; v6 = src[l + 384]; v7 = src[l + 448];
        }

        // stage 1 (H 64->16): lane handles output rows 8h..8h+7, column col
        const float* b = sw + h * 1024 + col;   // padded row 32h
        float o0 = TAP8(b, 0);
        float o1 = TAP8(b, 4);
        float o2 = TAP8(b, 8);
        float o3 = TAP8(b, 12);
        float o4 = TAP8(b, 16);
        float o5 = TAP8(b, 20);
        float o6 = TAP8(b, 24);
        float o7 = TAP8(b, 28);
        if (h == 0) o0 *= EDGE; else o7 *= EDGE;   // output rows 0 and 15

        float* tw = st + (8 * h) * TMP_STRIDE + 2 + col;
        tw[0]               = o0;
        tw[TMP_STRIDE]      = o1;
        tw[2 * TMP_STRIDE]  = o2;
        tw[3 * TMP_STRIDE]  = o3;
        tw[4 * TMP_STRIDE]  = o4;
        tw[5 * TMP_STRIDE]  = o5;
        tw[6 * TMP_STRIDE]  = o6;
        tw[7 * TMP_STRIDE]  = o7;

        // stage 2 (W 32->8): lane owns positions l and l+64
        const float* b2 = st + (l >> 3) * TMP_STRIDE + 4 * oc;
        float olo = W0*b2[0] + W1*b2[1] + W2*b2[2] + W3*b2[3]
                  + W3*b2[4] + W2*b2[5] + W1*b2[6] + W0*b2[7];
        const float* b3 = b2 + 8 * TMP_STRIDE;
        float ohi = W0*b3[0] + W1*b3[1] + W2*b3[2] + W3*b3[3]
                  + W3*b3[4] + W2*b3[5] + W1*b3[6] + W0*b3[7];
        olo *= cs2; ohi *= cs2;

        // group accumulation (c wave-uniform -> scalar branch)
        if (c < 5)       { ga0l += olo; ga0h += ohi; }
        else if (c < 11) { ga1l += olo; ga1h += ohi; }
        else             { ga2l += olo; ga2h += ohi; }

        // per-channel max/argmax over 128 positions (first-index tiebreak)
        {
            float bv; int bi;
            if (ohi > olo) { bv = ohi; bi = l + 64; } else { bv = olo; bi = l; }
#pragma unroll
            for (int off = 32; off >= 1; off >>= 1) {
                float ov = __shfl_down(bv, off);
                int   oi = __shfl_down(bi, off);
                if (ov > bv || (ov == bv && oi < bi)) { bv = ov; bi = oi; }
            }
            if (l == 0) {
                s_cval[c] = bv;
                float* mi = out_mi + ((size_t)n * N_CH + c) * 2;
                mi[0] = (float)(bi & 7);
                mi[1] = (float)(bi >> 3);
            }
        }
    }

    __syncthreads();                 // ONLY block-wide sync: main loop done
    float* s_part = s_in;            // overlay [4 waves][3 groups][128]
    s_part[(w * 3 + 0) * HW + l]      = ga0l;
    s_part[(w * 3 + 0) * HW + l + 64] = ga0h;
    s_part[(w * 3 + 1) * HW + l]      = ga1l;
    s_part[(w * 3 + 1) * HW + l + 64] = ga1h;
    s_part[(w * 3 + 2) * HW + l]      = ga2l;
    s_part[(w * 3 + 2) * HW + l + 64] = ga2h;
    __syncthreads();

    if (w < 3) {
        const int g = w;   // softmax over 128 positions of group g, one wave
        float lo = s_part[(0 * 3 + g) * HW + l]      + s_part[(1 * 3 + g) * HW + l]
                 + s_part[(2 * 3 + g) * HW + l]      + s_part[(3 * 3 + g) * HW + l];
        float hi = s_part[(0 * 3 + g) * HW + l + 64] + s_part[(1 * 3 + g) * HW + l + 64]
                 + s_part[(2 * 3 + g) * HW + l + 64] + s_part[(3 * 3 + g) * HW + l + 64];
        float m = fmaxf(lo, hi);
#pragma unroll
        for (int off = 1; off < 64; off <<= 1) m = fmaxf(m, __shfl_xor(m, off));
        float e0 = expf(lo - m), e1 = expf(hi - m);
        float s = e0 + e1;
#pragma unroll
        for (int off = 1; off < 64; off <<= 1) s += __shfl_xor(s, off);
        float inv = 1.f / s;
        float* dsto = out_heat + ((size_t)n * 3 + g) * HW;
        dsto[l]      = e0 * inv;
        dsto[l + 64] = e1 * inv;
    } else if (l < 3) {
        // wave 3: group means of per-channel maxes
        int lo = (l == 0) ? 0 : ((l == 1) ? 5 : 11);
        int hi = (l == 0) ? 5 : ((l == 1) ? 11 : 17);
        float acc = 0.f;
        for (int c2 = lo; c2 < hi; ++c2) acc += s_cval[c2];
        out_mr[(size_t)n * 3 + l] = acc / (float)(hi - lo);
    }
}

extern "C" void kernel_launch(void* const* d_in, const int* in_sizes, int n_in,
                              void* d_out, int out_size, void* d_ws, size_t ws_size,
                              hipStream_t stream) {
    const float* x = (const float*)d_in[0];
    float* out = (float*)d_out;
    const int N = in_sizes[0] / (N_CH * 64 * 32);      // 2048
    float* out_heat = out;                             // N*3*128
    float* out_mr   = out_heat + (size_t)N * 3 * HW;   // N*3
    float* out_mi   = out_mr + (size_t)N * 3;          // N*17*2
    heatmap_kernel<<<dim3(N), dim3(256), 0, stream>>>(x, out_heat, out_mr, out_mi);
}